// Round 17
// baseline (53.210 us; speedup 1.0000x reference)
//
#include <hip/hip_runtime.h>
#include <math.h>
#include <limits.h>

namespace {

constexpr int B_ = 16;
constexpr int H_ = 512;
constexpr int W_ = 512;
constexpr int HW_ = H_ * W_;
constexpr int CAP_ = 4096;           // one slot per 8x8 sub-block per image
constexpr int NSEL_ = 500;
constexpr int NTILE_ = B_ * 256;     // 4096 tile blocks
constexpr int NPART_ = NTILE_ + B_;  // partial-sum slots (base chunks + select)

typedef float f32x4 __attribute__((ext_vector_type(4)));
typedef float f32x2 __attribute__((ext_vector_type(2)));

__device__ inline f32x4 ld4(const float* p) { return *(const f32x4*)p; }
__device__ inline f32x2 ld2(const float* p) { return *(const f32x2*)p; }

// fast clamped log(1-p): v_log-based native log (~3 instr vs ~35 for log1pf).
// |err| ~6e-8 absolute from 1-p rounding; loss threshold is 2e-2.
__device__ inline float fast_l1p(float p) {
  return fmaxf(__logf(1.0f - p), -100.f);
}

// XCD-chunked bijective swizzle (4096 % 8 == 0): each XCD gets 512
// consecutive logical tiles (2 whole images) -> halo re-reads hit that
// XCD's L2; k_nms re-reads resp from the same L2 that wrote it.
__device__ inline int swz(int hw) { return (hw & 7) * 512 + (hw >> 3); }

// 7-tap gaussian, sigma=1, normalized (matches reference's np.exp/sum)
__device__ constexpr float GW[7] = {
    0.004433048175243746f, 0.05400558262251428f, 0.24203622937611957f,
    0.3990502796522496f,  0.24203622937611957f, 0.05400558262251428f,
    0.004433048175243746f};

__device__ inline int reflect_i(int i, int n) {
  // jnp.pad mode='reflect': -1 -> 1, n -> n-2
  return i < 0 ? -i : (i > n - 1 ? 2 * (n - 1) - i : i);
}

// k_resp LDS layout (phase-aliased, 4 blocks/CU: 36,976 B):
//   [0, 20064)        p_s[3][38][44]  (stride 44 words)
//   [20064, 36960)    P1-P2: g_s[40][40] (dead after P2)
//                     P3-P4: v_s[3][32][44] (written after barrier)
//   [36960, 36976)    wsum[4]
constexpr int OFF_G = 20064;
constexpr int OFF_W = 36960;
constexpr int SMEM_RESP = 36976;

// K1: imgs -> GFTT response map. One block = one 32x32 output tile.
// Interior tiles: float4 paths, no clamps; P1/P2 use 2-row items (single
// iteration, amortized addressing). P3 uses a 10-row register sliding
// window. Also absorbs the BCE base chunk for 1024 scores.
// Block 0 resets the k_select done-counter.
__global__ __launch_bounds__(256) void k_resp(const float* __restrict__ imgs,
                                              const float* __restrict__ scores,
                                              float* __restrict__ resp,
                                              double* __restrict__ part,
                                              int* __restrict__ done) {
  int hwbid = blockIdx.x;
  int bid = swz(hwbid);
  int bx = bid & 15, by = (bid >> 4) & 15, b = bid >> 8;
  int r0 = by * 32, c0 = bx * 32;
  __shared__ __align__(16) char smem[SMEM_RESP];
  float (*p_s)[38][44] = reinterpret_cast<float (*)[38][44]>(smem);
  float (*g_s)[40] = reinterpret_cast<float (*)[40]>(smem + OFF_G);
  float (*v_s)[32][44] = reinterpret_cast<float (*)[32][44]>(smem + OFF_G);
  float* wsum = reinterpret_cast<float*>(smem + OFF_W);
  int tid = threadIdx.x;
  const float* img = imgs + (size_t)b * 3 * HW_;
  bool interior = (bx >= 1 && bx <= 14 && by >= 1 && by <= 14);

  if (hwbid == 0 && tid == 0) done[0] = 0;  // consumed 2 dispatches later

  // BCE base chunk (hw-contiguous): issue load now, consume at the end.
  f32x4 sc = ld4(scores + (size_t)hwbid * 1024 + tid * 4);

  if (interior) {
    // Phase 1: grayscale, 20 row-pairs x 10 f32x4 cols = 200 items, 1 iter.
    if (tid < 200) {
      int rp = tid / 10, cg = tid % 10;
      int row = rp * 2, c4 = cg * 4;
      int o = (r0 - 4 + row) * W_ + (c0 - 4 + c4);
      f32x4 R0 = ld4(&img[o]);
      f32x4 G0 = ld4(&img[HW_ + o]);
      f32x4 B0 = ld4(&img[2 * HW_ + o]);
      f32x4 R1 = ld4(&img[o + W_]);
      f32x4 G1 = ld4(&img[HW_ + o + W_]);
      f32x4 B1 = ld4(&img[2 * HW_ + o + W_]);
      *(f32x4*)&g_s[row][c4]     = 0.299f * R0 + 0.587f * G0 + 0.114f * B0;
      *(f32x4*)&g_s[row + 1][c4] = 0.299f * R1 + 0.587f * G1 + 0.114f * B1;
    }
    __syncthreads();
    // Phase 2: gradient products, 19 row-pairs x 10 col-groups = 190 items.
    if (tid < 190) {
      int rp = tid / 10, cg = tid % 10;
      int pr = rp * 2, c = cg * 4;
      f32x4 a0 = ld4(&g_s[pr][c]);     f32x2 e0 = ld2(&g_s[pr][c + 4]);
      f32x4 a1 = ld4(&g_s[pr + 1][c]); f32x2 e1 = ld2(&g_s[pr + 1][c + 4]);
      f32x4 a2 = ld4(&g_s[pr + 2][c]); f32x2 e2 = ld2(&g_s[pr + 2][c + 4]);
      f32x4 a3 = ld4(&g_s[pr + 3][c]); f32x2 e3 = ld2(&g_s[pr + 3][c + 4]);
      float q0[6] = {a0[0], a0[1], a0[2], a0[3], e0[0], e0[1]};
      float q1[6] = {a1[0], a1[1], a1[2], a1[3], e1[0], e1[1]};
      float q2[6] = {a2[0], a2[1], a2[2], a2[3], e2[0], e2[1]};
      float q3[6] = {a3[0], a3[1], a3[2], a3[3], e3[0], e3[1]};
      const float cc = 1.f / 64.f;  // sobel /8 twice, folded
      f32x4 P0, P1, P2, Q0, Q1, Q2;
#pragma unroll
      for (int j = 0; j < 4; j++) {
        // row pr (gray rows q0..q2)
        float dxr = (q0[j + 2] - q0[j]) + 2.f * (q1[j + 2] - q1[j]) + (q2[j + 2] - q2[j]);
        float dyr = (q2[j] - q0[j]) + 2.f * (q2[j + 1] - q0[j + 1]) + (q2[j + 2] - q0[j + 2]);
        float t = dxr * cc, u = dyr * cc;
        P0[j] = t * dxr; P1[j] = u * dyr; P2[j] = t * dyr;
        // row pr+1 (gray rows q1..q3)
        float dxs = (q1[j + 2] - q1[j]) + 2.f * (q2[j + 2] - q2[j]) + (q3[j + 2] - q3[j]);
        float dys = (q3[j] - q1[j]) + 2.f * (q3[j + 1] - q1[j + 1]) + (q3[j + 2] - q1[j + 2]);
        float t2 = dxs * cc, u2 = dys * cc;
        Q0[j] = t2 * dxs; Q1[j] = u2 * dys; Q2[j] = t2 * dys;
      }
      *(f32x4*)&p_s[0][pr][c] = P0;
      *(f32x4*)&p_s[1][pr][c] = P1;
      *(f32x4*)&p_s[2][pr][c] = P2;
      *(f32x4*)&p_s[0][pr + 1][c] = Q0;
      *(f32x4*)&p_s[1][pr + 1][c] = Q1;
      *(f32x4*)&p_s[2][pr + 1][c] = Q2;
    }
  } else {
    // border tiles: scalar path with replicate clamp + reflect (proven)
    for (int l = tid; l < 40 * 40; l += 256) {
      int lr = l / 40, lc = l % 40;
      int gr = min(max(r0 - 4 + lr, 0), H_ - 1);
      int gc = min(max(c0 - 4 + lc, 0), W_ - 1);
      int o = gr * W_ + gc;
      g_s[lr][lc] = 0.299f * img[o] + 0.587f * img[HW_ + o] + 0.114f * img[2 * HW_ + o];
    }
    __syncthreads();
    for (int l = tid; l < 38 * 38; l += 256) {
      int lr = l / 38, lc = l % 38;
      int ar = reflect_i(r0 - 3 + lr, H_);
      int ac = reflect_i(c0 - 3 + lc, W_);
      int rm = max(ar - 1, 0)      - (r0 - 4);
      int rz = ar                  - (r0 - 4);
      int rp = min(ar + 1, H_ - 1) - (r0 - 4);
      int cm = max(ac - 1, 0)      - (c0 - 4);
      int cz = ac                  - (c0 - 4);
      int cp = min(ac + 1, W_ - 1) - (c0 - 4);
      float gnw = g_s[rm][cm], gn = g_s[rm][cz], gne = g_s[rm][cp];
      float gw_ = g_s[rz][cm],                   ge  = g_s[rz][cp];
      float gsw = g_s[rp][cm], gs = g_s[rp][cz], gse = g_s[rp][cp];
      float dx = ((gne - gnw) + 2.f * (ge - gw_) + (gse - gsw)) * 0.125f;
      float dy = ((gsw - gnw) + 2.f * (gs - gn) + (gse - gne)) * 0.125f;
      p_s[0][lr][lc] = dx * dx;
      p_s[1][lr][lc] = dy * dy;
      p_s[2][lr][lc] = dx * dy;
    }
  }
  __syncthreads();   // after this barrier g_s is dead; v_s takes its bytes

  // Phase 3: vertical 7-tap blur via register sliding window.
  // item = (ch, row-quad, col-group): 3*8*10 = 240 items, 1 per thread.
  if (tid < 240) {
    int ch = tid / 80;
    int rq = (tid / 10) % 8;
    int cg = tid % 10;
    int c = cg * 4;
    int vr0 = rq * 4;
    f32x4 w[10];
#pragma unroll
    for (int k = 0; k < 10; k++) w[k] = ld4(&p_s[ch][vr0 + k][c]);
#pragma unroll
    for (int j = 0; j < 4; j++) {
      f32x4 s = {0.f, 0.f, 0.f, 0.f};
#pragma unroll
      for (int t = 0; t < 7; t++) s += GW[t] * w[j + t];
      *(f32x4*)&v_s[ch][vr0 + j][c] = s;
    }
  }
  __syncthreads();

  // Phase 4: horizontal blur + response, 32 rows x 8 groups = 1 per thread.
  {
    int r = tid >> 3;
    int c = (tid & 7) << 2;
    float wa[3][10];
#pragma unroll
    for (int ch = 0; ch < 3; ch++) {
      f32x4 x = ld4(&v_s[ch][r][c]);
      f32x4 y = ld4(&v_s[ch][r][c + 4]);
      f32x2 z = ld2(&v_s[ch][r][c + 8]);
      wa[ch][0] = x[0]; wa[ch][1] = x[1]; wa[ch][2] = x[2]; wa[ch][3] = x[3];
      wa[ch][4] = y[0]; wa[ch][5] = y[1]; wa[ch][6] = y[2]; wa[ch][7] = y[3];
      wa[ch][8] = z[0]; wa[ch][9] = z[1];
    }
    f32x4 outv;
#pragma unroll
    for (int j = 0; j < 4; j++) {
      float b0 = 0.f, b1 = 0.f, b2 = 0.f;
#pragma unroll
      for (int t = 0; t < 7; t++) {
        b0 += GW[t] * wa[0][j + t];
        b1 += GW[t] * wa[1][j + t];
        b2 += GW[t] * wa[2][j + t];
      }
      float tr = b0 + b1;
      float det = b0 * b1 - b2 * b2;
      // v_sqrt_f32 (~1ulp): all consumers compare STORED resp values, so
      // equality semantics stay internally consistent.
      outv[j] = 0.5f * (tr - __builtin_amdgcn_sqrtf(fabsf(tr * tr - 4.f * det) + 1e-12f));
    }
    *(f32x4*)&resp[((size_t)b * H_ + (r0 + r)) * W_ + (c0 + c)] = outv;
  }

  // BCE base chunk reduce -> part[hwbid] (bijective slots; order-independent)
  float s = fast_l1p(sc[0]) + fast_l1p(sc[1]) + fast_l1p(sc[2]) + fast_l1p(sc[3]);
  for (int off = 32; off > 0; off >>= 1) s += __shfl_down(s, off);
  if ((tid & 63) == 0) wsum[tid >> 6] = s;
  __syncthreads();
  if (tid == 0) {
    double t = (double)wsum[0] + (double)wsum[1] + (double)wsum[2] + (double)wsum[3];
    part[hwbid] = t;  // deterministic slot, overwritten every call
  }
}

// K2: 5x5 NMS via SEPARABLE max (row-max then col-max) + per-8x8-block max
// into deterministic cand slot. Same XCD swizzle as k_resp -> resp halo
// reads hit the writing XCD's L2.
__global__ __launch_bounds__(256) void k_nms(const float* __restrict__ resp,
                                             float* __restrict__ cand_val,
                                             int* __restrict__ cand_idx) {
  int bid = swz((int)blockIdx.x);
  int bx = bid & 15, by = (bid >> 4) & 15, b = bid >> 8;
  int r0 = by * 32, c0 = bx * 32;
  __shared__ __align__(16) float r_s[36][40];
  __shared__ float rm_s[36][32];
  __shared__ float c_s[32][32];
  int tid = threadIdx.x;

  const float* rb = resp + (size_t)b * HW_;
  bool interior = (bx >= 1 && bx <= 14 && by >= 1 && by <= 14);
  if (interior) {
    // rows r0-2..r0+33, cols c0-4..c0+35 (aligned f32x4), 36 x 10 groups
    for (int l = tid; l < 360; l += 256) {
      int lr = l / 10, c4 = (l % 10) * 4;
      *(f32x4*)&r_s[lr][c4] = ld4(&rb[(r0 - 2 + lr) * W_ + (c0 - 4 + c4)]);
    }
  } else {
    for (int l = tid; l < 36 * 40; l += 256) {
      int lr = l / 40, lc = l % 40;
      int gr = r0 - 2 + lr, gc = c0 - 4 + lc;
      float v = -INFINITY;
      if (gr >= 0 && gr < H_ && gc >= 0 && gc < W_) v = rb[gr * W_ + gc];
      r_s[lr][lc] = v;
    }
  }
  __syncthreads();

  // row-max: rm[r][c] = max over r_s[r][c+2..c+6]  (center col = c+4)
  for (int l = tid; l < 1152; l += 256) {
    int r = l >> 5, c = l & 31;
    float m = fmaxf(fmaxf(fmaxf(r_s[r][c + 2], r_s[r][c + 3]),
                          fmaxf(r_s[r][c + 4], r_s[r][c + 5])),
                    r_s[r][c + 6]);
    rm_s[r][c] = m;
  }
  __syncthreads();

  // col-max + keep-if-equal (x == 5x5 maxpool)
  for (int l = tid; l < 1024; l += 256) {
    int r = l >> 5, c = l & 31;
    float m = fmaxf(fmaxf(fmaxf(rm_s[r][c], rm_s[r + 1][c]),
                          fmaxf(rm_s[r + 2][c], rm_s[r + 3][c])),
                    rm_s[r + 4][c]);
    float v = r_s[r + 2][c + 4];
    c_s[r][c] = (v == m) ? v : 0.f;
  }
  __syncthreads();

  // per-8x8-block max into deterministic cand slot (min-idx tiebreak)
  if (tid < 16) {
    int sr = (tid >> 2) << 3, sc_ = (tid & 3) << 3;
    float m = 0.f;
    int mi = INT_MAX;
#pragma unroll
    for (int u = 0; u < 8; u++)
      for (int w = 0; w < 8; w++) {
        float v = c_s[sr + u][sc_ + w];
        if (v > m) { m = v; mi = (r0 + sr + u) * W_ + (c0 + sc_ + w); }
      }
    int subg = ((r0 + sr) >> 3) * 64 + ((c0 + sc_) >> 3);
    bool pos = (m > 0.f);
    cand_val[b * CAP_ + subg] = pos ? m : -INFINITY;
    cand_idx[b * CAP_ + subg] = pos ? mi : INT_MAX;
  }
}

// K3: per-image top-500 via MSB-first RADIX SELECT (no sort) + fused FINAL
// REDUCE: the last block (done-counter, reset by k_resp) sums all partials
// and writes the loss. Items in registers (4/thread); 4 passes x 8 bits:
// LDS histogram + wave-0 parallel suffix-scan. Second nms2d is a provable
// no-op, so every selected positive item is a corner.
__global__ __launch_bounds__(1024) void k_select(const float* __restrict__ cand_val,
                                                 const int* __restrict__ cand_idx,
                                                 const float* __restrict__ scores,
                                                 double* __restrict__ part,
                                                 int* __restrict__ done,
                                                 float* __restrict__ out) {
  int b = blockIdx.x;
  __shared__ unsigned hist[256];
  __shared__ unsigned s_prefix;
  __shared__ int s_rank;
  __shared__ int eq_idx[1024];
  __shared__ int eq_cnt;
  __shared__ float wsum[16];
  __shared__ double dsum[16];
  __shared__ int s_last;
  int tid = threadIdx.x;

  unsigned key[4];
  int idx[4];
#pragma unroll
  for (int q = 0; q < 4; q++) {
    int l = tid + q * 1024;
    float v = cand_val[b * CAP_ + l];
    idx[q] = cand_idx[b * CAP_ + l];
    unsigned u = __float_as_uint(v);
    key[q] = (u & 0x80000000u) ? ~u : (u | 0x80000000u);  // order-preserving
  }
  if (tid == 0) { s_rank = NSEL_; s_prefix = 0; eq_cnt = 0; }

  for (int pass = 0; pass < 4; pass++) {
    int shift = 24 - 8 * pass;
    if (tid < 256) hist[tid] = 0;
    __syncthreads();
    unsigned pref = s_prefix;   // read-before-write: writes after next barrier
    int rank = s_rank;
#pragma unroll
    for (int q = 0; q < 4; q++) {
      bool match = (pass == 0) || ((key[q] >> (shift + 8)) == pref);
      if (match) atomicAdd(&hist[(key[q] >> shift) & 255u], 1u);
    }
    __syncthreads();
    if (tid < 64) {
      unsigned h0 = hist[tid * 4 + 0], h1 = hist[tid * 4 + 1];
      unsigned h2 = hist[tid * 4 + 2], h3 = hist[tid * 4 + 3];
      unsigned tot = h0 + h1 + h2 + h3;
      unsigned suf = tot;  // suffix sum over lanes >= tid
#pragma unroll
      for (int off = 1; off < 64; off <<= 1) {
        unsigned o = __shfl_down(suf, off);
        if (tid + off < 64) suf += o;
      }
      unsigned above3 = suf - tot;
      unsigned above2 = above3 + h3;
      unsigned above1 = above2 + h2;
      unsigned above0 = above1 + h1;
      unsigned r = (unsigned)rank;
      if (above0 < r && r <= above0 + h0) { s_rank = (int)(r - above0); s_prefix = (pref << 8) | (unsigned)(tid * 4 + 0); }
      if (above1 < r && r <= above1 + h1) { s_rank = (int)(r - above1); s_prefix = (pref << 8) | (unsigned)(tid * 4 + 1); }
      if (above2 < r && r <= above2 + h2) { s_rank = (int)(r - above2); s_prefix = (pref << 8) | (unsigned)(tid * 4 + 2); }
      if (above3 < r && r <= above3 + h3) { s_rank = (int)(r - above3); s_prefix = (pref << 8) | (unsigned)(tid * 4 + 3); }
    }
    __syncthreads();
  }
  unsigned T = s_prefix;
  int need = s_rank;

#pragma unroll
  for (int q = 0; q < 4; q++) {
    if (key[q] == T) {
      int pos = atomicAdd(&eq_cnt, 1);
      if (pos < 1024) eq_idx[pos] = idx[q];
    }
  }
  __syncthreads();
  int E = min(eq_cnt, 1024);

  const unsigned KPOS = 0x80000000u;  // key of +0.0; corners need value > 0
  float term = 0.f;
#pragma unroll
  for (int q = 0; q < 4; q++) {
    bool corner = false;
    if (key[q] > KPOS) {
      if (key[q] > T) {
        corner = true;
      } else if (key[q] == T) {
        int r = 0;
        for (int j = 0; j < E; j++) r += (eq_idx[j] < idx[q]);
        corner = (r < need);
      }
    }
    if (corner) {
      float p = scores[(size_t)b * HW_ + idx[q]];
      term += fmaxf(__logf(p), -100.f) - fast_l1p(p);
    }
  }
  for (int off = 32; off > 0; off >>= 1) term += __shfl_down(term, off);
  if ((tid & 63) == 0) wsum[tid >> 6] = term;
  __syncthreads();
  if (tid == 0) {
    double s = 0.0;
    for (int i = 0; i < 16; i++) s += (double)wsum[i];
    // release-store our partial, then bump the done counter (acq_rel)
    __hip_atomic_store(&part[NTILE_ + b], s, __ATOMIC_RELEASE,
                       __HIP_MEMORY_SCOPE_AGENT);
    int old = __hip_atomic_fetch_add(done, 1, __ATOMIC_ACQ_REL,
                                     __HIP_MEMORY_SCOPE_AGENT);
    s_last = (old == B_ - 1) ? 1 : 0;
  }
  __syncthreads();
  if (!s_last) return;

  // FINAL REDUCE (last block only): k_resp partials are 2 dispatches old
  // (plain loads safe); sibling k_select partials via atomic-acquire loads.
  double s = 0.0;
  for (int i = tid; i < NTILE_; i += 1024) s += part[i];
  if (tid < B_)
    s += __hip_atomic_load(&part[NTILE_ + tid], __ATOMIC_ACQUIRE,
                           __HIP_MEMORY_SCOPE_AGENT);
  for (int off = 32; off > 0; off >>= 1) s += __shfl_down(s, off);
  if ((tid & 63) == 0) dsum[tid >> 6] = s;
  __syncthreads();
  if (tid == 0) {
    double t = 0.0;
    for (int i = 0; i < 16; i++) t += dsum[i];
    out[0] = (float)(-t / (double)((size_t)B_ * HW_));
  }
}

}  // namespace

extern "C" void kernel_launch(void* const* d_in, const int* in_sizes, int n_in,
                              void* d_out, int out_size, void* d_ws, size_t ws_size,
                              hipStream_t stream) {
  const float* scores = (const float*)d_in[0];
  const float* imgs = (const float*)d_in[1];
  float* out = (float*)d_out;

  char* ws = (char*)d_ws;
  double* part = (double*)ws;                          // NPART_ doubles (32,896 B)
  int* done = (int*)(ws + 32896);                      // 4 B counter
  float* resp = (float*)(ws + 33024);                  // 16 MB, 16B-aligned
  float* cand_val = resp + (size_t)B_ * HW_;           // 16*4096 f32
  int* cand_idx = (int*)(cand_val + B_ * CAP_);        // 16*4096 i32

  k_resp<<<NTILE_, 256, 0, stream>>>(imgs, scores, resp, part, done);
  k_nms<<<NTILE_, 256, 0, stream>>>(resp, cand_val, cand_idx);
  k_select<<<B_, 1024, 0, stream>>>(cand_val, cand_idx, scores, part, done, out);
}

// Round 18
// 53.123 us; speedup vs baseline: 1.0016x; 1.0016x over previous
//
#include <hip/hip_runtime.h>
#include <math.h>
#include <limits.h>

namespace {

constexpr int B_ = 16;
constexpr int H_ = 512;
constexpr int W_ = 512;
constexpr int HW_ = H_ * W_;
constexpr int CAP_ = 4096;           // one slot per 8x8 sub-block per image
constexpr int NSEL_ = 500;
constexpr int NTILE_ = B_ * 256;     // 4096 tile blocks
constexpr int NPART_ = NTILE_ + B_;  // partial-sum slots (base chunks + select)

typedef float f32x4 __attribute__((ext_vector_type(4)));
typedef float f32x2 __attribute__((ext_vector_type(2)));

__device__ inline f32x4 ld4(const float* p) { return *(const f32x4*)p; }
__device__ inline f32x2 ld2(const float* p) { return *(const f32x2*)p; }

// fast clamped log(1-p): v_log-based native log (~3 instr vs ~35 for log1pf).
// |err| ~6e-8 absolute from 1-p rounding; loss threshold is 2e-2.
__device__ inline float fast_l1p(float p) {
  return fmaxf(__logf(1.0f - p), -100.f);
}

// XCD-chunked bijective swizzle (4096 % 8 == 0): each XCD gets 512
// consecutive logical tiles (2 whole images) -> halo re-reads hit that
// XCD's L2; k_nms re-reads resp from the same L2 that wrote it.
__device__ inline int swz(int hw) { return (hw & 7) * 512 + (hw >> 3); }

// 7-tap gaussian, sigma=1, normalized (matches reference's np.exp/sum)
__device__ constexpr float GW[7] = {
    0.004433048175243746f, 0.05400558262251428f, 0.24203622937611957f,
    0.3990502796522496f,  0.24203622937611957f, 0.05400558262251428f,
    0.004433048175243746f};

__device__ inline int reflect_i(int i, int n) {
  // jnp.pad mode='reflect': -1 -> 1, n -> n-2
  return i < 0 ? -i : (i > n - 1 ? 2 * (n - 1) - i : i);
}

// k_resp LDS layout (phase-aliased, 4 blocks/CU: 36,976 B):
//   [0, 20064)        p_s[3][38][44]  (stride 44 words)
//   [20064, 36960)    P1-P2: g_s[40][40] (dead after P2)
//                     P3-P4: v_s[3][32][44] (written after barrier)
//   [36960, 36976)    wsum[4]
constexpr int OFF_G = 20064;
constexpr int OFF_W = 36960;
constexpr int SMEM_RESP = 36976;

// K1: imgs -> GFTT response map. One block = one 32x32 output tile.
// Interior tiles: float4 paths, no clamps; P1/P2 use 2-row items (single
// iteration, amortized addressing). P3 uses a 10-row register sliding
// window. Also absorbs the BCE base chunk for 1024 scores.
// Block 0 resets the k_select done-counter.
__global__ __launch_bounds__(256) void k_resp(const float* __restrict__ imgs,
                                              const float* __restrict__ scores,
                                              float* __restrict__ resp,
                                              double* __restrict__ part,
                                              int* __restrict__ done) {
  int hwbid = blockIdx.x;
  int bid = swz(hwbid);
  int bx = bid & 15, by = (bid >> 4) & 15, b = bid >> 8;
  int r0 = by * 32, c0 = bx * 32;
  __shared__ __align__(16) char smem[SMEM_RESP];
  float (*p_s)[38][44] = reinterpret_cast<float (*)[38][44]>(smem);
  float (*g_s)[40] = reinterpret_cast<float (*)[40]>(smem + OFF_G);
  float (*v_s)[32][44] = reinterpret_cast<float (*)[32][44]>(smem + OFF_G);
  float* wsum = reinterpret_cast<float*>(smem + OFF_W);
  int tid = threadIdx.x;
  const float* img = imgs + (size_t)b * 3 * HW_;
  bool interior = (bx >= 1 && bx <= 14 && by >= 1 && by <= 14);

  if (hwbid == 0 && tid == 0) done[0] = 0;  // consumed 2 dispatches later

  // BCE base chunk (hw-contiguous): issue load now, consume at the end.
  f32x4 sc = ld4(scores + (size_t)hwbid * 1024 + tid * 4);

  if (interior) {
    // Phase 1: grayscale, 20 row-pairs x 10 f32x4 cols = 200 items, 1 iter.
    if (tid < 200) {
      int rp = tid / 10, cg = tid % 10;
      int row = rp * 2, c4 = cg * 4;
      int o = (r0 - 4 + row) * W_ + (c0 - 4 + c4);
      f32x4 R0 = ld4(&img[o]);
      f32x4 G0 = ld4(&img[HW_ + o]);
      f32x4 B0 = ld4(&img[2 * HW_ + o]);
      f32x4 R1 = ld4(&img[o + W_]);
      f32x4 G1 = ld4(&img[HW_ + o + W_]);
      f32x4 B1 = ld4(&img[2 * HW_ + o + W_]);
      *(f32x4*)&g_s[row][c4]     = 0.299f * R0 + 0.587f * G0 + 0.114f * B0;
      *(f32x4*)&g_s[row + 1][c4] = 0.299f * R1 + 0.587f * G1 + 0.114f * B1;
    }
    __syncthreads();
    // Phase 2: gradient products, 19 row-pairs x 10 col-groups = 190 items.
    if (tid < 190) {
      int rp = tid / 10, cg = tid % 10;
      int pr = rp * 2, c = cg * 4;
      f32x4 a0 = ld4(&g_s[pr][c]);     f32x2 e0 = ld2(&g_s[pr][c + 4]);
      f32x4 a1 = ld4(&g_s[pr + 1][c]); f32x2 e1 = ld2(&g_s[pr + 1][c + 4]);
      f32x4 a2 = ld4(&g_s[pr + 2][c]); f32x2 e2 = ld2(&g_s[pr + 2][c + 4]);
      f32x4 a3 = ld4(&g_s[pr + 3][c]); f32x2 e3 = ld2(&g_s[pr + 3][c + 4]);
      float q0[6] = {a0[0], a0[1], a0[2], a0[3], e0[0], e0[1]};
      float q1[6] = {a1[0], a1[1], a1[2], a1[3], e1[0], e1[1]};
      float q2[6] = {a2[0], a2[1], a2[2], a2[3], e2[0], e2[1]};
      float q3[6] = {a3[0], a3[1], a3[2], a3[3], e3[0], e3[1]};
      const float cc = 1.f / 64.f;  // sobel /8 twice, folded
      f32x4 P0, P1, P2, Q0, Q1, Q2;
#pragma unroll
      for (int j = 0; j < 4; j++) {
        // row pr (gray rows q0..q2)
        float dxr = (q0[j + 2] - q0[j]) + 2.f * (q1[j + 2] - q1[j]) + (q2[j + 2] - q2[j]);
        float dyr = (q2[j] - q0[j]) + 2.f * (q2[j + 1] - q0[j + 1]) + (q2[j + 2] - q0[j + 2]);
        float t = dxr * cc, u = dyr * cc;
        P0[j] = t * dxr; P1[j] = u * dyr; P2[j] = t * dyr;
        // row pr+1 (gray rows q1..q3)
        float dxs = (q1[j + 2] - q1[j]) + 2.f * (q2[j + 2] - q2[j]) + (q3[j + 2] - q3[j]);
        float dys = (q3[j] - q1[j]) + 2.f * (q3[j + 1] - q1[j + 1]) + (q3[j + 2] - q1[j + 2]);
        float t2 = dxs * cc, u2 = dys * cc;
        Q0[j] = t2 * dxs; Q1[j] = u2 * dys; Q2[j] = t2 * dys;
      }
      *(f32x4*)&p_s[0][pr][c] = P0;
      *(f32x4*)&p_s[1][pr][c] = P1;
      *(f32x4*)&p_s[2][pr][c] = P2;
      *(f32x4*)&p_s[0][pr + 1][c] = Q0;
      *(f32x4*)&p_s[1][pr + 1][c] = Q1;
      *(f32x4*)&p_s[2][pr + 1][c] = Q2;
    }
  } else {
    // border tiles: scalar path with replicate clamp + reflect (proven)
    for (int l = tid; l < 40 * 40; l += 256) {
      int lr = l / 40, lc = l % 40;
      int gr = min(max(r0 - 4 + lr, 0), H_ - 1);
      int gc = min(max(c0 - 4 + lc, 0), W_ - 1);
      int o = gr * W_ + gc;
      g_s[lr][lc] = 0.299f * img[o] + 0.587f * img[HW_ + o] + 0.114f * img[2 * HW_ + o];
    }
    __syncthreads();
    for (int l = tid; l < 38 * 38; l += 256) {
      int lr = l / 38, lc = l % 38;
      int ar = reflect_i(r0 - 3 + lr, H_);
      int ac = reflect_i(c0 - 3 + lc, W_);
      int rm = max(ar - 1, 0)      - (r0 - 4);
      int rz = ar                  - (r0 - 4);
      int rp = min(ar + 1, H_ - 1) - (r0 - 4);
      int cm = max(ac - 1, 0)      - (c0 - 4);
      int cz = ac                  - (c0 - 4);
      int cp = min(ac + 1, W_ - 1) - (c0 - 4);
      float gnw = g_s[rm][cm], gn = g_s[rm][cz], gne = g_s[rm][cp];
      float gw_ = g_s[rz][cm],                   ge  = g_s[rz][cp];
      float gsw = g_s[rp][cm], gs = g_s[rp][cz], gse = g_s[rp][cp];
      float dx = ((gne - gnw) + 2.f * (ge - gw_) + (gse - gsw)) * 0.125f;
      float dy = ((gsw - gnw) + 2.f * (gs - gn) + (gse - gne)) * 0.125f;
      p_s[0][lr][lc] = dx * dx;
      p_s[1][lr][lc] = dy * dy;
      p_s[2][lr][lc] = dx * dy;
    }
  }
  __syncthreads();   // after this barrier g_s is dead; v_s takes its bytes

  // Phase 3: vertical 7-tap blur via register sliding window.
  // item = (ch, row-quad, col-group): 3*8*10 = 240 items, 1 per thread.
  if (tid < 240) {
    int ch = tid / 80;
    int rq = (tid / 10) % 8;
    int cg = tid % 10;
    int c = cg * 4;
    int vr0 = rq * 4;
    f32x4 w[10];
#pragma unroll
    for (int k = 0; k < 10; k++) w[k] = ld4(&p_s[ch][vr0 + k][c]);
#pragma unroll
    for (int j = 0; j < 4; j++) {
      f32x4 s = {0.f, 0.f, 0.f, 0.f};
#pragma unroll
      for (int t = 0; t < 7; t++) s += GW[t] * w[j + t];
      *(f32x4*)&v_s[ch][vr0 + j][c] = s;
    }
  }
  __syncthreads();

  // Phase 4: horizontal blur + response, 32 rows x 8 groups = 1 per thread.
  {
    int r = tid >> 3;
    int c = (tid & 7) << 2;
    float wa[3][10];
#pragma unroll
    for (int ch = 0; ch < 3; ch++) {
      f32x4 x = ld4(&v_s[ch][r][c]);
      f32x4 y = ld4(&v_s[ch][r][c + 4]);
      f32x2 z = ld2(&v_s[ch][r][c + 8]);
      wa[ch][0] = x[0]; wa[ch][1] = x[1]; wa[ch][2] = x[2]; wa[ch][3] = x[3];
      wa[ch][4] = y[0]; wa[ch][5] = y[1]; wa[ch][6] = y[2]; wa[ch][7] = y[3];
      wa[ch][8] = z[0]; wa[ch][9] = z[1];
    }
    f32x4 outv;
#pragma unroll
    for (int j = 0; j < 4; j++) {
      float b0 = 0.f, b1 = 0.f, b2 = 0.f;
#pragma unroll
      for (int t = 0; t < 7; t++) {
        b0 += GW[t] * wa[0][j + t];
        b1 += GW[t] * wa[1][j + t];
        b2 += GW[t] * wa[2][j + t];
      }
      float tr = b0 + b1;
      float det = b0 * b1 - b2 * b2;
      // v_sqrt_f32 (~1ulp): all consumers compare STORED resp values, so
      // equality semantics stay internally consistent.
      outv[j] = 0.5f * (tr - __builtin_amdgcn_sqrtf(fabsf(tr * tr - 4.f * det) + 1e-12f));
    }
    *(f32x4*)&resp[((size_t)b * H_ + (r0 + r)) * W_ + (c0 + c)] = outv;
  }

  // BCE base chunk reduce -> part[hwbid] (bijective slots; order-independent)
  float s = fast_l1p(sc[0]) + fast_l1p(sc[1]) + fast_l1p(sc[2]) + fast_l1p(sc[3]);
  for (int off = 32; off > 0; off >>= 1) s += __shfl_down(s, off);
  if ((tid & 63) == 0) wsum[tid >> 6] = s;
  __syncthreads();
  if (tid == 0) {
    double t = (double)wsum[0] + (double)wsum[1] + (double)wsum[2] + (double)wsum[3];
    part[hwbid] = t;  // deterministic slot, overwritten every call
  }
}

// K2: 5x5 NMS via SEPARABLE max (row-max then col-max) + per-8x8-block max
// into deterministic cand slot. Same XCD swizzle as k_resp -> resp halo
// reads hit the writing XCD's L2.
__global__ __launch_bounds__(256) void k_nms(const float* __restrict__ resp,
                                             float* __restrict__ cand_val,
                                             int* __restrict__ cand_idx) {
  int bid = swz((int)blockIdx.x);
  int bx = bid & 15, by = (bid >> 4) & 15, b = bid >> 8;
  int r0 = by * 32, c0 = bx * 32;
  __shared__ __align__(16) float r_s[36][40];
  __shared__ float rm_s[36][32];
  __shared__ float c_s[32][32];
  int tid = threadIdx.x;

  const float* rb = resp + (size_t)b * HW_;
  bool interior = (bx >= 1 && bx <= 14 && by >= 1 && by <= 14);
  if (interior) {
    // rows r0-2..r0+33, cols c0-4..c0+35 (aligned f32x4), 36 x 10 groups
    for (int l = tid; l < 360; l += 256) {
      int lr = l / 10, c4 = (l % 10) * 4;
      *(f32x4*)&r_s[lr][c4] = ld4(&rb[(r0 - 2 + lr) * W_ + (c0 - 4 + c4)]);
    }
  } else {
    for (int l = tid; l < 36 * 40; l += 256) {
      int lr = l / 40, lc = l % 40;
      int gr = r0 - 2 + lr, gc = c0 - 4 + lc;
      float v = -INFINITY;
      if (gr >= 0 && gr < H_ && gc >= 0 && gc < W_) v = rb[gr * W_ + gc];
      r_s[lr][lc] = v;
    }
  }
  __syncthreads();

  // row-max: rm[r][c] = max over r_s[r][c+2..c+6]  (center col = c+4)
  for (int l = tid; l < 1152; l += 256) {
    int r = l >> 5, c = l & 31;
    float m = fmaxf(fmaxf(fmaxf(r_s[r][c + 2], r_s[r][c + 3]),
                          fmaxf(r_s[r][c + 4], r_s[r][c + 5])),
                    r_s[r][c + 6]);
    rm_s[r][c] = m;
  }
  __syncthreads();

  // col-max + keep-if-equal (x == 5x5 maxpool)
  for (int l = tid; l < 1024; l += 256) {
    int r = l >> 5, c = l & 31;
    float m = fmaxf(fmaxf(fmaxf(rm_s[r][c], rm_s[r + 1][c]),
                          fmaxf(rm_s[r + 2][c], rm_s[r + 3][c])),
                    rm_s[r + 4][c]);
    float v = r_s[r + 2][c + 4];
    c_s[r][c] = (v == m) ? v : 0.f;
  }
  __syncthreads();

  // per-8x8-block max into deterministic cand slot (min-idx tiebreak)
  if (tid < 16) {
    int sr = (tid >> 2) << 3, sc_ = (tid & 3) << 3;
    float m = 0.f;
    int mi = INT_MAX;
#pragma unroll
    for (int u = 0; u < 8; u++)
      for (int w = 0; w < 8; w++) {
        float v = c_s[sr + u][sc_ + w];
        if (v > m) { m = v; mi = (r0 + sr + u) * W_ + (c0 + sc_ + w); }
      }
    int subg = ((r0 + sr) >> 3) * 64 + ((c0 + sc_) >> 3);
    bool pos = (m > 0.f);
    cand_val[b * CAP_ + subg] = pos ? m : -INFINITY;
    cand_idx[b * CAP_ + subg] = pos ? mi : INT_MAX;
  }
}

// K3: per-image top-500 via MSB-first RADIX SELECT (no sort) + fused FINAL
// REDUCE: the last block (done-counter, reset by k_resp) sums all partials
// and writes the loss. Items in registers (4/thread); 4 passes x 8 bits:
// LDS histogram + wave-0 parallel suffix-scan. Second nms2d is a provable
// no-op, so every selected positive item is a corner.
__global__ __launch_bounds__(1024) void k_select(const float* __restrict__ cand_val,
                                                 const int* __restrict__ cand_idx,
                                                 const float* __restrict__ scores,
                                                 double* __restrict__ part,
                                                 int* __restrict__ done,
                                                 float* __restrict__ out) {
  int b = blockIdx.x;
  __shared__ unsigned hist[256];
  __shared__ unsigned s_prefix;
  __shared__ int s_rank;
  __shared__ int eq_idx[1024];
  __shared__ int eq_cnt;
  __shared__ float wsum[16];
  __shared__ double dsum[16];
  __shared__ int s_last;
  int tid = threadIdx.x;

  unsigned key[4];
  int idx[4];
#pragma unroll
  for (int q = 0; q < 4; q++) {
    int l = tid + q * 1024;
    float v = cand_val[b * CAP_ + l];
    idx[q] = cand_idx[b * CAP_ + l];
    unsigned u = __float_as_uint(v);
    key[q] = (u & 0x80000000u) ? ~u : (u | 0x80000000u);  // order-preserving
  }
  if (tid == 0) { s_rank = NSEL_; s_prefix = 0; eq_cnt = 0; }

  for (int pass = 0; pass < 4; pass++) {
    int shift = 24 - 8 * pass;
    if (tid < 256) hist[tid] = 0;
    __syncthreads();
    unsigned pref = s_prefix;   // read-before-write: writes after next barrier
    int rank = s_rank;
#pragma unroll
    for (int q = 0; q < 4; q++) {
      bool match = (pass == 0) || ((key[q] >> (shift + 8)) == pref);
      if (match) atomicAdd(&hist[(key[q] >> shift) & 255u], 1u);
    }
    __syncthreads();
    if (tid < 64) {
      unsigned h0 = hist[tid * 4 + 0], h1 = hist[tid * 4 + 1];
      unsigned h2 = hist[tid * 4 + 2], h3 = hist[tid * 4 + 3];
      unsigned tot = h0 + h1 + h2 + h3;
      unsigned suf = tot;  // suffix sum over lanes >= tid
#pragma unroll
      for (int off = 1; off < 64; off <<= 1) {
        unsigned o = __shfl_down(suf, off);
        if (tid + off < 64) suf += o;
      }
      unsigned above3 = suf - tot;
      unsigned above2 = above3 + h3;
      unsigned above1 = above2 + h2;
      unsigned above0 = above1 + h1;
      unsigned r = (unsigned)rank;
      if (above0 < r && r <= above0 + h0) { s_rank = (int)(r - above0); s_prefix = (pref << 8) | (unsigned)(tid * 4 + 0); }
      if (above1 < r && r <= above1 + h1) { s_rank = (int)(r - above1); s_prefix = (pref << 8) | (unsigned)(tid * 4 + 1); }
      if (above2 < r && r <= above2 + h2) { s_rank = (int)(r - above2); s_prefix = (pref << 8) | (unsigned)(tid * 4 + 2); }
      if (above3 < r && r <= above3 + h3) { s_rank = (int)(r - above3); s_prefix = (pref << 8) | (unsigned)(tid * 4 + 3); }
    }
    __syncthreads();
  }
  unsigned T = s_prefix;
  int need = s_rank;

#pragma unroll
  for (int q = 0; q < 4; q++) {
    if (key[q] == T) {
      int pos = atomicAdd(&eq_cnt, 1);
      if (pos < 1024) eq_idx[pos] = idx[q];
    }
  }
  __syncthreads();
  int E = min(eq_cnt, 1024);

  const unsigned KPOS = 0x80000000u;  // key of +0.0; corners need value > 0
  float term = 0.f;
#pragma unroll
  for (int q = 0; q < 4; q++) {
    bool corner = false;
    if (key[q] > KPOS) {
      if (key[q] > T) {
        corner = true;
      } else if (key[q] == T) {
        int r = 0;
        for (int j = 0; j < E; j++) r += (eq_idx[j] < idx[q]);
        corner = (r < need);
      }
    }
    if (corner) {
      float p = scores[(size_t)b * HW_ + idx[q]];
      term += fmaxf(__logf(p), -100.f) - fast_l1p(p);
    }
  }
  for (int off = 32; off > 0; off >>= 1) term += __shfl_down(term, off);
  if ((tid & 63) == 0) wsum[tid >> 6] = term;
  __syncthreads();
  if (tid == 0) {
    double s = 0.0;
    for (int i = 0; i < 16; i++) s += (double)wsum[i];
    // release-store our partial, then bump the done counter (acq_rel)
    __hip_atomic_store(&part[NTILE_ + b], s, __ATOMIC_RELEASE,
                       __HIP_MEMORY_SCOPE_AGENT);
    int old = __hip_atomic_fetch_add(done, 1, __ATOMIC_ACQ_REL,
                                     __HIP_MEMORY_SCOPE_AGENT);
    s_last = (old == B_ - 1) ? 1 : 0;
  }
  __syncthreads();
  if (!s_last) return;

  // FINAL REDUCE (last block only): k_resp partials are 2 dispatches old
  // (plain loads safe); sibling k_select partials via atomic-acquire loads.
  double s = 0.0;
  for (int i = tid; i < NTILE_; i += 1024) s += part[i];
  if (tid < B_)
    s += __hip_atomic_load(&part[NTILE_ + tid], __ATOMIC_ACQUIRE,
                           __HIP_MEMORY_SCOPE_AGENT);
  for (int off = 32; off > 0; off >>= 1) s += __shfl_down(s, off);
  if ((tid & 63) == 0) dsum[tid >> 6] = s;
  __syncthreads();
  if (tid == 0) {
    double t = 0.0;
    for (int i = 0; i < 16; i++) t += dsum[i];
    out[0] = (float)(-t / (double)((size_t)B_ * HW_));
  }
}

}  // namespace

extern "C" void kernel_launch(void* const* d_in, const int* in_sizes, int n_in,
                              void* d_out, int out_size, void* d_ws, size_t ws_size,
                              hipStream_t stream) {
  const float* scores = (const float*)d_in[0];
  const float* imgs = (const float*)d_in[1];
  float* out = (float*)d_out;

  char* ws = (char*)d_ws;
  double* part = (double*)ws;                          // NPART_ doubles (32,896 B)
  int* done = (int*)(ws + 32896);                      // 4 B counter
  float* resp = (float*)(ws + 33024);                  // 16 MB, 16B-aligned
  float* cand_val = resp + (size_t)B_ * HW_;           // 16*4096 f32
  int* cand_idx = (int*)(cand_val + B_ * CAP_);        // 16*4096 i32

  k_resp<<<NTILE_, 256, 0, stream>>>(imgs, scores, resp, part, done);
  k_nms<<<NTILE_, 256, 0, stream>>>(resp, cand_val, cand_idx);
  k_select<<<B_, 1024, 0, stream>>>(cand_val, cand_idx, scores, part, done, out);
}

// Round 19
// 50.903 us; speedup vs baseline: 1.0453x; 1.0436x over previous
//
#include <hip/hip_runtime.h>
#include <math.h>
#include <limits.h>

namespace {

constexpr int B_ = 16;
constexpr int H_ = 512;
constexpr int W_ = 512;
constexpr int HW_ = H_ * W_;
constexpr int CAP_ = 4096;           // one slot per 8x8 sub-block per image
constexpr int NSEL_ = 500;
constexpr int NTILE_ = B_ * 256;     // 4096 tile blocks
constexpr int NPART_ = NTILE_ + B_;  // partial-sum slots (base chunks + select)

typedef float f32x4 __attribute__((ext_vector_type(4)));
typedef float f32x2 __attribute__((ext_vector_type(2)));

__device__ inline f32x4 ld4(const float* p) { return *(const f32x4*)p; }
__device__ inline f32x2 ld2(const float* p) { return *(const f32x2*)p; }

// fast clamped log(1-p): v_log-based native log (~3 instr vs ~35 for log1pf).
// |err| ~6e-8 absolute from 1-p rounding; loss threshold is 2e-2.
__device__ inline float fast_l1p(float p) {
  return fmaxf(__logf(1.0f - p), -100.f);
}

// XCD-chunked bijective swizzle (4096 % 8 == 0): each XCD gets 512
// consecutive logical tiles (2 whole images) -> halo re-reads hit that
// XCD's L2; k_nms re-reads resp from the same L2 that wrote it.
__device__ inline int swz(int hw) { return (hw & 7) * 512 + (hw >> 3); }

// Border-first tile order within an image: t in [0,256) -> (bx,by) with the
// 60 border tiles (expensive scalar path) first so they aren't stragglers.
__device__ inline void tile_map(int t, int& bx, int& by) {
  if (t < 60) {
    if (t < 16)      { by = 0;      bx = t; }
    else if (t < 32) { by = 15;     bx = t - 16; }
    else if (t < 46) { by = t - 31; bx = 0; }    // by 1..14
    else             { by = t - 45; bx = 15; }   // by 1..14
  } else {
    int r = t - 60;
    by = 1 + r / 14;
    bx = 1 + r % 14;
  }
}

// 7-tap gaussian, sigma=1, normalized (matches reference's np.exp/sum)
__device__ constexpr float GW[7] = {
    0.004433048175243746f, 0.05400558262251428f, 0.24203622937611957f,
    0.3990502796522496f,  0.24203622937611957f, 0.05400558262251428f,
    0.004433048175243746f};

__device__ inline int reflect_i(int i, int n) {
  // jnp.pad mode='reflect': -1 -> 1, n -> n-2
  return i < 0 ? -i : (i > n - 1 ? 2 * (n - 1) - i : i);
}

// k_resp LDS layout (phase-aliased, 4 blocks/CU: 36,976 B):
//   [0, 20064)        p_s[3][38][44]  (stride 44 words)
//   [20064, 36960)    P1-P2: g_s[40][40] (dead after P2)
//                     P3-P4: v_s[3][32][44] (written after barrier)
//   [36960, 36976)    wsum[4]
constexpr int OFF_G = 20064;
constexpr int OFF_W = 36960;
constexpr int SMEM_RESP = 36976;

// K1: imgs -> GFTT response map. One block = one 32x32 output tile.
// Interior tiles: float4 paths, no clamps; P1/P2 use 2-row items. P3 uses a
// 10-row register sliding window. Also absorbs the BCE base chunk for 1024
// scores. Block 0 resets the k_select done-counter.
__global__ __launch_bounds__(256) void k_resp(const float* __restrict__ imgs,
                                              const float* __restrict__ scores,
                                              float* __restrict__ resp,
                                              double* __restrict__ part,
                                              int* __restrict__ done) {
  int hwbid = blockIdx.x;
  int bid = swz(hwbid);
  int b = bid >> 8;
  int bx, by;
  tile_map(bid & 255, bx, by);
  int r0 = by * 32, c0 = bx * 32;
  __shared__ __align__(16) char smem[SMEM_RESP];
  float (*p_s)[38][44] = reinterpret_cast<float (*)[38][44]>(smem);
  float (*g_s)[40] = reinterpret_cast<float (*)[40]>(smem + OFF_G);
  float (*v_s)[32][44] = reinterpret_cast<float (*)[32][44]>(smem + OFF_G);
  float* wsum = reinterpret_cast<float*>(smem + OFF_W);
  int tid = threadIdx.x;
  const float* img = imgs + (size_t)b * 3 * HW_;
  bool interior = (bx >= 1 && bx <= 14 && by >= 1 && by <= 14);

  if (hwbid == 0 && tid == 0) done[0] = 0;  // consumed 2 dispatches later

  // BCE base chunk (hw-contiguous): issue load now, consume at the end.
  f32x4 sc = ld4(scores + (size_t)hwbid * 1024 + tid * 4);

  if (interior) {
    // Phase 1: grayscale, 20 row-pairs x 10 f32x4 cols = 200 items, 1 iter.
    if (tid < 200) {
      int rp = tid / 10, cg = tid % 10;
      int row = rp * 2, c4 = cg * 4;
      int o = (r0 - 4 + row) * W_ + (c0 - 4 + c4);
      f32x4 R0 = ld4(&img[o]);
      f32x4 G0 = ld4(&img[HW_ + o]);
      f32x4 B0 = ld4(&img[2 * HW_ + o]);
      f32x4 R1 = ld4(&img[o + W_]);
      f32x4 G1 = ld4(&img[HW_ + o + W_]);
      f32x4 B1 = ld4(&img[2 * HW_ + o + W_]);
      *(f32x4*)&g_s[row][c4]     = 0.299f * R0 + 0.587f * G0 + 0.114f * B0;
      *(f32x4*)&g_s[row + 1][c4] = 0.299f * R1 + 0.587f * G1 + 0.114f * B1;
    }
    __syncthreads();
    // Phase 2: gradient products, 19 row-pairs x 10 col-groups = 190 items.
    if (tid < 190) {
      int rp = tid / 10, cg = tid % 10;
      int pr = rp * 2, c = cg * 4;
      f32x4 a0 = ld4(&g_s[pr][c]);     f32x2 e0 = ld2(&g_s[pr][c + 4]);
      f32x4 a1 = ld4(&g_s[pr + 1][c]); f32x2 e1 = ld2(&g_s[pr + 1][c + 4]);
      f32x4 a2 = ld4(&g_s[pr + 2][c]); f32x2 e2 = ld2(&g_s[pr + 2][c + 4]);
      f32x4 a3 = ld4(&g_s[pr + 3][c]); f32x2 e3 = ld2(&g_s[pr + 3][c + 4]);
      float q0[6] = {a0[0], a0[1], a0[2], a0[3], e0[0], e0[1]};
      float q1[6] = {a1[0], a1[1], a1[2], a1[3], e1[0], e1[1]};
      float q2[6] = {a2[0], a2[1], a2[2], a2[3], e2[0], e2[1]};
      float q3[6] = {a3[0], a3[1], a3[2], a3[3], e3[0], e3[1]};
      const float cc = 1.f / 64.f;  // sobel /8 twice, folded
      f32x4 P0, P1, P2, Q0, Q1, Q2;
#pragma unroll
      for (int j = 0; j < 4; j++) {
        float dxr = (q0[j + 2] - q0[j]) + 2.f * (q1[j + 2] - q1[j]) + (q2[j + 2] - q2[j]);
        float dyr = (q2[j] - q0[j]) + 2.f * (q2[j + 1] - q0[j + 1]) + (q2[j + 2] - q0[j + 2]);
        float t = dxr * cc, u = dyr * cc;
        P0[j] = t * dxr; P1[j] = u * dyr; P2[j] = t * dyr;
        float dxs = (q1[j + 2] - q1[j]) + 2.f * (q2[j + 2] - q2[j]) + (q3[j + 2] - q3[j]);
        float dys = (q3[j] - q1[j]) + 2.f * (q3[j + 1] - q1[j + 1]) + (q3[j + 2] - q1[j + 2]);
        float t2 = dxs * cc, u2 = dys * cc;
        Q0[j] = t2 * dxs; Q1[j] = u2 * dys; Q2[j] = t2 * dys;
      }
      *(f32x4*)&p_s[0][pr][c] = P0;
      *(f32x4*)&p_s[1][pr][c] = P1;
      *(f32x4*)&p_s[2][pr][c] = P2;
      *(f32x4*)&p_s[0][pr + 1][c] = Q0;
      *(f32x4*)&p_s[1][pr + 1][c] = Q1;
      *(f32x4*)&p_s[2][pr + 1][c] = Q2;
    }
  } else {
    // border tiles: scalar path with replicate clamp + reflect (proven)
    for (int l = tid; l < 40 * 40; l += 256) {
      int lr = l / 40, lc = l % 40;
      int gr = min(max(r0 - 4 + lr, 0), H_ - 1);
      int gc = min(max(c0 - 4 + lc, 0), W_ - 1);
      int o = gr * W_ + gc;
      g_s[lr][lc] = 0.299f * img[o] + 0.587f * img[HW_ + o] + 0.114f * img[2 * HW_ + o];
    }
    __syncthreads();
    for (int l = tid; l < 38 * 38; l += 256) {
      int lr = l / 38, lc = l % 38;
      int ar = reflect_i(r0 - 3 + lr, H_);
      int ac = reflect_i(c0 - 3 + lc, W_);
      int rm = max(ar - 1, 0)      - (r0 - 4);
      int rz = ar                  - (r0 - 4);
      int rp = min(ar + 1, H_ - 1) - (r0 - 4);
      int cm = max(ac - 1, 0)      - (c0 - 4);
      int cz = ac                  - (c0 - 4);
      int cp = min(ac + 1, W_ - 1) - (c0 - 4);
      float gnw = g_s[rm][cm], gn = g_s[rm][cz], gne = g_s[rm][cp];
      float gw_ = g_s[rz][cm],                   ge  = g_s[rz][cp];
      float gsw = g_s[rp][cm], gs = g_s[rp][cz], gse = g_s[rp][cp];
      float dx = ((gne - gnw) + 2.f * (ge - gw_) + (gse - gsw)) * 0.125f;
      float dy = ((gsw - gnw) + 2.f * (gs - gn) + (gse - gne)) * 0.125f;
      p_s[0][lr][lc] = dx * dx;
      p_s[1][lr][lc] = dy * dy;
      p_s[2][lr][lc] = dx * dy;
    }
  }
  __syncthreads();   // after this barrier g_s is dead; v_s takes its bytes

  // Phase 3: vertical 7-tap blur via register sliding window.
  // item = (ch, row-quad, col-group): 3*8*10 = 240 items, 1 per thread.
  if (tid < 240) {
    int ch = tid / 80;
    int rq = (tid / 10) % 8;
    int cg = tid % 10;
    int c = cg * 4;
    int vr0 = rq * 4;
    f32x4 w[10];
#pragma unroll
    for (int k = 0; k < 10; k++) w[k] = ld4(&p_s[ch][vr0 + k][c]);
#pragma unroll
    for (int j = 0; j < 4; j++) {
      f32x4 s = {0.f, 0.f, 0.f, 0.f};
#pragma unroll
      for (int t = 0; t < 7; t++) s += GW[t] * w[j + t];
      *(f32x4*)&v_s[ch][vr0 + j][c] = s;
    }
  }
  __syncthreads();

  // Phase 4: horizontal blur + response, 32 rows x 8 groups = 1 per thread.
  {
    int r = tid >> 3;
    int c = (tid & 7) << 2;
    float wa[3][10];
#pragma unroll
    for (int ch = 0; ch < 3; ch++) {
      f32x4 x = ld4(&v_s[ch][r][c]);
      f32x4 y = ld4(&v_s[ch][r][c + 4]);
      f32x2 z = ld2(&v_s[ch][r][c + 8]);
      wa[ch][0] = x[0]; wa[ch][1] = x[1]; wa[ch][2] = x[2]; wa[ch][3] = x[3];
      wa[ch][4] = y[0]; wa[ch][5] = y[1]; wa[ch][6] = y[2]; wa[ch][7] = y[3];
      wa[ch][8] = z[0]; wa[ch][9] = z[1];
    }
    f32x4 outv;
#pragma unroll
    for (int j = 0; j < 4; j++) {
      float b0 = 0.f, b1 = 0.f, b2 = 0.f;
#pragma unroll
      for (int t = 0; t < 7; t++) {
        b0 += GW[t] * wa[0][j + t];
        b1 += GW[t] * wa[1][j + t];
        b2 += GW[t] * wa[2][j + t];
      }
      float tr = b0 + b1;
      float det = b0 * b1 - b2 * b2;
      // v_sqrt_f32 (~1ulp): all consumers compare STORED resp values.
      outv[j] = 0.5f * (tr - __builtin_amdgcn_sqrtf(fabsf(tr * tr - 4.f * det) + 1e-12f));
    }
    *(f32x4*)&resp[((size_t)b * H_ + (r0 + r)) * W_ + (c0 + c)] = outv;
  }

  // BCE base chunk reduce -> part[hwbid] (bijective slots; order-independent)
  float s = fast_l1p(sc[0]) + fast_l1p(sc[1]) + fast_l1p(sc[2]) + fast_l1p(sc[3]);
  for (int off = 32; off > 0; off >>= 1) s += __shfl_down(s, off);
  if ((tid & 63) == 0) wsum[tid >> 6] = s;
  __syncthreads();
  if (tid == 0) {
    double t = (double)wsum[0] + (double)wsum[1] + (double)wsum[2] + (double)wsum[3];
    part[hwbid] = t;  // deterministic slot, overwritten every call
  }
}

// K2: 5x5 NMS via SEPARABLE max (row-max then col-max) + per-8x8-block
// argmax via 16-lane shfl reduce (no serial tail) into deterministic cand
// slot. Same XCD swizzle -> resp reads hit the writing XCD's L2.
__global__ __launch_bounds__(256) void k_nms(const float* __restrict__ resp,
                                             float* __restrict__ cand_val,
                                             int* __restrict__ cand_idx) {
  int bid = swz((int)blockIdx.x);
  int bx = bid & 15, by = (bid >> 4) & 15, b = bid >> 8;
  int r0 = by * 32, c0 = bx * 32;
  __shared__ __align__(16) float r_s[36][40];
  __shared__ float rm_s[36][32];
  __shared__ float c_s[32][32];
  int tid = threadIdx.x;

  const float* rb = resp + (size_t)b * HW_;
  bool interior = (bx >= 1 && bx <= 14 && by >= 1 && by <= 14);
  if (interior) {
    // rows r0-2..r0+33, cols c0-4..c0+35 (aligned f32x4), 36 x 10 groups
    for (int l = tid; l < 360; l += 256) {
      int lr = l / 10, c4 = (l % 10) * 4;
      *(f32x4*)&r_s[lr][c4] = ld4(&rb[(r0 - 2 + lr) * W_ + (c0 - 4 + c4)]);
    }
  } else {
    for (int l = tid; l < 36 * 40; l += 256) {
      int lr = l / 40, lc = l % 40;
      int gr = r0 - 2 + lr, gc = c0 - 4 + lc;
      float v = -INFINITY;
      if (gr >= 0 && gr < H_ && gc >= 0 && gc < W_) v = rb[gr * W_ + gc];
      r_s[lr][lc] = v;
    }
  }
  __syncthreads();

  // row-max: rm[r][c] = max over r_s[r][c+2..c+6]  (center col = c+4)
  for (int l = tid; l < 1152; l += 256) {
    int r = l >> 5, c = l & 31;
    float m = fmaxf(fmaxf(fmaxf(r_s[r][c + 2], r_s[r][c + 3]),
                          fmaxf(r_s[r][c + 4], r_s[r][c + 5])),
                    r_s[r][c + 6]);
    rm_s[r][c] = m;
  }
  __syncthreads();

  // col-max + keep-if-equal (x == 5x5 maxpool)
  for (int l = tid; l < 1024; l += 256) {
    int r = l >> 5, c = l & 31;
    float m = fmaxf(fmaxf(fmaxf(rm_s[r][c], rm_s[r + 1][c]),
                          fmaxf(rm_s[r + 2][c], rm_s[r + 3][c])),
                    rm_s[r + 4][c]);
    float v = r_s[r + 2][c + 4];
    c_s[r][c] = (v == m) ? v : 0.f;
  }
  __syncthreads();

  // per-8x8-block argmax (value desc, idx asc): thread (sub=tid>>4, k=tid&15)
  // scans 4 cells in idx order, then 4-step shfl_xor reduce over the 16-lane
  // sub-group (xor offsets <16 stay within the group on a 64-wide wave).
  {
    int sub = tid >> 4, k = tid & 15;
    int sr = (sub >> 2) << 3, sc_ = (sub & 3) << 3;
    float m = 0.f;
    int mi = INT_MAX;
#pragma unroll
    for (int c = 0; c < 4; c++) {
      int cell = k * 4 + c;
      int u = cell >> 3, w = cell & 7;
      float v = c_s[sr + u][sc_ + w];
      if (v > m) { m = v; mi = (r0 + sr + u) * W_ + (c0 + sc_ + w); }
    }
#pragma unroll
    for (int off = 1; off < 16; off <<= 1) {
      float m2 = __shfl_xor(m, off);
      int mi2 = __shfl_xor(mi, off);
      if (m2 > m || (m2 == m && mi2 < mi)) { m = m2; mi = mi2; }
    }
    if (k == 0) {
      int subg = ((r0 + sr) >> 3) * 64 + ((c0 + sc_) >> 3);
      bool pos = (m > 0.f);
      cand_val[b * CAP_ + subg] = pos ? m : -INFINITY;
      cand_idx[b * CAP_ + subg] = pos ? mi : INT_MAX;
    }
  }
}

// K3: per-image top-500 via MSB-first RADIX SELECT (no sort) + fused FINAL
// REDUCE: the last block (done-counter, reset by k_resp) sums all partials
// and writes the loss. Items in registers (4/thread); 4 passes x 8 bits:
// LDS histogram + wave-0 parallel suffix-scan. Second nms2d is a provable
// no-op, so every selected positive item is a corner.
__global__ __launch_bounds__(1024) void k_select(const float* __restrict__ cand_val,
                                                 const int* __restrict__ cand_idx,
                                                 const float* __restrict__ scores,
                                                 double* __restrict__ part,
                                                 int* __restrict__ done,
                                                 float* __restrict__ out) {
  int b = blockIdx.x;
  __shared__ unsigned hist[256];
  __shared__ unsigned s_prefix;
  __shared__ int s_rank;
  __shared__ int eq_idx[1024];
  __shared__ int eq_cnt;
  __shared__ float wsum[16];
  __shared__ double dsum[16];
  __shared__ int s_last;
  int tid = threadIdx.x;

  unsigned key[4];
  int idx[4];
#pragma unroll
  for (int q = 0; q < 4; q++) {
    int l = tid + q * 1024;
    float v = cand_val[b * CAP_ + l];
    idx[q] = cand_idx[b * CAP_ + l];
    unsigned u = __float_as_uint(v);
    key[q] = (u & 0x80000000u) ? ~u : (u | 0x80000000u);  // order-preserving
  }
  if (tid == 0) { s_rank = NSEL_; s_prefix = 0; eq_cnt = 0; }

  for (int pass = 0; pass < 4; pass++) {
    int shift = 24 - 8 * pass;
    if (tid < 256) hist[tid] = 0;
    __syncthreads();
    unsigned pref = s_prefix;   // read-before-write: writes after next barrier
    int rank = s_rank;
#pragma unroll
    for (int q = 0; q < 4; q++) {
      bool match = (pass == 0) || ((key[q] >> (shift + 8)) == pref);
      if (match) atomicAdd(&hist[(key[q] >> shift) & 255u], 1u);
    }
    __syncthreads();
    if (tid < 64) {
      unsigned h0 = hist[tid * 4 + 0], h1 = hist[tid * 4 + 1];
      unsigned h2 = hist[tid * 4 + 2], h3 = hist[tid * 4 + 3];
      unsigned tot = h0 + h1 + h2 + h3;
      unsigned suf = tot;  // suffix sum over lanes >= tid
#pragma unroll
      for (int off = 1; off < 64; off <<= 1) {
        unsigned o = __shfl_down(suf, off);
        if (tid + off < 64) suf += o;
      }
      unsigned above3 = suf - tot;
      unsigned above2 = above3 + h3;
      unsigned above1 = above2 + h2;
      unsigned above0 = above1 + h1;
      unsigned r = (unsigned)rank;
      if (above0 < r && r <= above0 + h0) { s_rank = (int)(r - above0); s_prefix = (pref << 8) | (unsigned)(tid * 4 + 0); }
      if (above1 < r && r <= above1 + h1) { s_rank = (int)(r - above1); s_prefix = (pref << 8) | (unsigned)(tid * 4 + 1); }
      if (above2 < r && r <= above2 + h2) { s_rank = (int)(r - above2); s_prefix = (pref << 8) | (unsigned)(tid * 4 + 2); }
      if (above3 < r && r <= above3 + h3) { s_rank = (int)(r - above3); s_prefix = (pref << 8) | (unsigned)(tid * 4 + 3); }
    }
    __syncthreads();
  }
  unsigned T = s_prefix;
  int need = s_rank;

#pragma unroll
  for (int q = 0; q < 4; q++) {
    if (key[q] == T) {
      int pos = atomicAdd(&eq_cnt, 1);
      if (pos < 1024) eq_idx[pos] = idx[q];
    }
  }
  __syncthreads();
  int E = min(eq_cnt, 1024);

  const unsigned KPOS = 0x80000000u;  // key of +0.0; corners need value > 0
  float term = 0.f;
#pragma unroll
  for (int q = 0; q < 4; q++) {
    bool corner = false;
    if (key[q] > KPOS) {
      if (key[q] > T) {
        corner = true;
      } else if (key[q] == T) {
        int r = 0;
        for (int j = 0; j < E; j++) r += (eq_idx[j] < idx[q]);
        corner = (r < need);
      }
    }
    if (corner) {
      float p = scores[(size_t)b * HW_ + idx[q]];
      term += fmaxf(__logf(p), -100.f) - fast_l1p(p);
    }
  }
  for (int off = 32; off > 0; off >>= 1) term += __shfl_down(term, off);
  if ((tid & 63) == 0) wsum[tid >> 6] = term;
  __syncthreads();
  if (tid == 0) {
    double s = 0.0;
    for (int i = 0; i < 16; i++) s += (double)wsum[i];
    // release-store our partial, then bump the done counter (acq_rel)
    __hip_atomic_store(&part[NTILE_ + b], s, __ATOMIC_RELEASE,
                       __HIP_MEMORY_SCOPE_AGENT);
    int old = __hip_atomic_fetch_add(done, 1, __ATOMIC_ACQ_REL,
                                     __HIP_MEMORY_SCOPE_AGENT);
    s_last = (old == B_ - 1) ? 1 : 0;
  }
  __syncthreads();
  if (!s_last) return;

  // FINAL REDUCE (last block only): k_resp partials are 2 dispatches old
  // (plain loads safe); sibling k_select partials via atomic-acquire loads.
  double s = 0.0;
  for (int i = tid; i < NTILE_; i += 1024) s += part[i];
  if (tid < B_)
    s += __hip_atomic_load(&part[NTILE_ + tid], __ATOMIC_ACQUIRE,
                           __HIP_MEMORY_SCOPE_AGENT);
  for (int off = 32; off > 0; off >>= 1) s += __shfl_down(s, off);
  if ((tid & 63) == 0) dsum[tid >> 6] = s;
  __syncthreads();
  if (tid == 0) {
    double t = 0.0;
    for (int i = 0; i < 16; i++) t += dsum[i];
    out[0] = (float)(-t / (double)((size_t)B_ * HW_));
  }
}

}  // namespace

extern "C" void kernel_launch(void* const* d_in, const int* in_sizes, int n_in,
                              void* d_out, int out_size, void* d_ws, size_t ws_size,
                              hipStream_t stream) {
  const float* scores = (const float*)d_in[0];
  const float* imgs = (const float*)d_in[1];
  float* out = (float*)d_out;

  char* ws = (char*)d_ws;
  double* part = (double*)ws;                          // NPART_ doubles (32,896 B)
  int* done = (int*)(ws + 32896);                      // 4 B counter
  float* resp = (float*)(ws + 33024);                  // 16 MB, 16B-aligned
  float* cand_val = resp + (size_t)B_ * HW_;           // 16*4096 f32
  int* cand_idx = (int*)(cand_val + B_ * CAP_);        // 16*4096 i32

  k_resp<<<NTILE_, 256, 0, stream>>>(imgs, scores, resp, part, done);
  k_nms<<<NTILE_, 256, 0, stream>>>(resp, cand_val, cand_idx);
  k_select<<<B_, 1024, 0, stream>>>(cand_val, cand_idx, scores, part, done, out);
}